// Round 9
// baseline (95.170 us; speedup 1.0000x reference)
//
#include <hip/hip_runtime.h>
#include <math.h>

#define S 1024
#define D 64
#define BND 0.99999994f
#define FINF 3.4e38f
#define C4(v,c) ((&(v).x)[c])
#define FMA4(acc,s,v) { (acc).x+=(s)*(v).x; (acc).y+=(s)*(v).y; (acc).z+=(s)*(v).z; (acc).w+=(s)*(v).w; }

__device__ __forceinline__ float waveSum(float v){
  #pragma unroll
  for(int o=32;o>0;o>>=1) v += __shfl_xor(v,o,64);
  return v;
}
__device__ __forceinline__ float4 mk4(const float* a){
  float4 r; r.x=a[0]; r.y=a[1]; r.z=a[2]; r.w=a[3]; return r;
}
// 512-thread packed 2-value reductions (one barrier pair each).
__device__ __forceinline__ float2 blockSum512_v2(float2 v, float* red){
  #pragma unroll
  for(int o=32;o>0;o>>=1){ v.x+=__shfl_xor(v.x,o,64); v.y+=__shfl_xor(v.y,o,64); }
  const int wid=threadIdx.x>>6;
  __syncthreads();
  if((threadIdx.x&63)==0){ red[wid*2]=v.x; red[wid*2+1]=v.y; }
  __syncthreads();
  float2 s={0.f,0.f};
  #pragma unroll
  for(int k=0;k<8;k++){ s.x+=red[k*2]; s.y+=red[k*2+1]; }
  return s;
}
__device__ __forceinline__ float2 blockMin512_v2(float2 v, float* red){
  #pragma unroll
  for(int o=32;o>0;o>>=1){ v.x=fminf(v.x,__shfl_xor(v.x,o,64)); v.y=fminf(v.y,__shfl_xor(v.y,o,64)); }
  const int wid=threadIdx.x>>6;
  __syncthreads();
  if((threadIdx.x&63)==0){ red[wid*2]=v.x; red[wid*2+1]=v.y; }
  __syncthreads();
  float2 s={red[0],red[1]};
  #pragma unroll
  for(int k=1;k<8;k++){ s.x=fminf(s.x,red[k*2]); s.y=fminf(s.y,red[k*2+1]); }
  return s;
}

// K1: projections, expmap0(q/k), norms, v_r init, kT transpose, combined vk=[vproj|kproj]
__global__ __launch_bounds__(256) void k_proj(
  const float* __restrict__ qin, const float* __restrict__ kin, const float* __restrict__ vin,
  const float* __restrict__ Wq, const float* __restrict__ bq,
  const float* __restrict__ Wk, const float* __restrict__ bk,
  const float* __restrict__ Wv, const float* __restrict__ bv,
  const float* __restrict__ vrand,
  float* __restrict__ q_hyp, float* __restrict__ k_hyp, float* __restrict__ kT,
  float* __restrict__ vk,
  float* __restrict__ q2, float* __restrict__ k2, float* __restrict__ v_r)
{
  const int r=threadIdx.x>>6, d=threadIdx.x&63;
  const int i = blockIdx.x*4+r;
  __shared__ __align__(16) float lq[4][D], lk[4][D], lv[4][D];
  lq[r][d]=qin[i*D+d]; lk[r][d]=kin[i*D+d]; lv[r][d]=vin[i*D+d];
  __syncthreads();
  float aq=bq[d], ak=bk[d], av=bv[d];
  const float4* wq4=(const float4*)(Wq + d*D);
  const float4* wk4=(const float4*)(Wk + d*D);
  const float4* wv4=(const float4*)(Wv + d*D);
  #pragma unroll
  for(int e=0;e<16;e++){
    float4 a=wq4[e], b=wk4[e], c=wv4[e];
    aq += lq[r][4*e]*a.x + lq[r][4*e+1]*a.y + lq[r][4*e+2]*a.z + lq[r][4*e+3]*a.w;
    ak += lk[r][4*e]*b.x + lk[r][4*e+1]*b.y + lk[r][4*e+2]*b.z + lk[r][4*e+3]*b.w;
    av += lv[r][4*e]*c.x + lv[r][4*e+1]*c.y + lv[r][4*e+2]*c.z + lv[r][4*e+3]*c.w;
  }
  float nq = sqrtf(waveSum(aq*aq)+1e-15f);
  float qh = tanhf(nq)*aq/nq;
  q_hyp[i*D+d]=qh;
  float q2v = waveSum(qh*qh);
  if(d==0) q2[i]=q2v;
  float nk = sqrtf(waveSum(ak*ak)+1e-15f);
  float kh = tanhf(nk)*ak/nk;
  k_hyp[i*D+d]=kh;
  kT[(size_t)d*S + i]=kh;
  float k2v = waveSum(kh*kh);
  if(d==0) k2[i]=k2v;
  vk[(size_t)i*128 + d]      = av;   // vproj half
  vk[(size_t)i*128 + 64 + d] = ak;   // kproj half
  float vr = vrand[i*D+d];
  float nn = sqrtf(waveSum(vr*vr));
  v_r[i*D+d] = vr/fmaxf(nn,1e-12f);
}

// K2 (single fused kernel): QB=2, 512 threads, grid 512 (2 blocks/CU).
// P1: dist->min->w->wsum->entropy    (kT sweep)
// P2: h + centroid + expmap0 + cdot0 (one vk sweep, wave-split combine)
// PA: a,b coefs (LDS), var deferred  (kT sweep)
// PB: 3 power iterations             (kT sweep + k_hyp sweep each)
// PC: bifurcation epilogue + out GEMV
__global__ __launch_bounds__(512,4) void k_main(
  const float* __restrict__ q_hyp_g, const float* __restrict__ k_hyp,
  const float* __restrict__ kT,
  const float* __restrict__ q2a, const float* __restrict__ k2a,
  const float* __restrict__ vk, const float* __restrict__ v_r,
  const float* __restrict__ tau_p,
  const float* __restrict__ gu, const float* __restrict__ gamma_p,
  const float* __restrict__ ts_p, const float* __restrict__ Wo,
  const float* __restrict__ bo, float* __restrict__ out)
{
  const int i0=blockIdx.x*2, tid=threadIdx.x;
  __shared__ __align__(16) float qv[2][D];
  __shared__ __align__(16) float cv[2][D];
  __shared__ __align__(16) float vv[2][D];
  __shared__ __align__(16) float hl[2][D];
  __shared__ __align__(16) float fus[2][D];
  __shared__ __align__(16) float wl[2][S];     // w; aliased as prow in PB
  __shared__ __align__(16) float aal[2][S];
  __shared__ __align__(16) float bbl[2][S];
  __shared__ __align__(16) float4 sA[1024];    // 16KB: pjoin / part buffer
  __shared__ float red[16];
  __shared__ float varred[16];                 // [wave][q]
  __shared__ float salred[16];
  __shared__ float scal[2][4];                 // 0:c2 2:cdot
  float* const pA=(float*)sA;

  const int jf=tid&255, dh=tid>>8;
  const int dq=tid&15, g=tid>>4;               // 16x32 mapping (pass2 k_hyp)
  const int dq5=tid&31, g16=tid>>5;            // 32x16 mapping (vk sweep)
  const float tau=tau_p[0];
  const float4* kT4=(const float4*)kT;

  if(tid<128){
    const int q=tid>>6, d=tid&63;
    qv[q][d]=q_hyp_g[i0*D+tid];
    vv[q][d]=v_r[i0*D+tid];
  }
  __syncthreads();

  // ================= P1: weights =================
  {
    float4 p0={0,0,0,0}, p1={0,0,0,0};
    #pragma unroll 8
    for(int dd=0; dd<32; ++dd){
      const int d=(dh<<5)+dd;
      const float4 y=kT4[d*256+jf];
      const float c0=qv[0][d], c1=qv[1][d];
      FMA4(p0,c0,y); FMA4(p1,c1,y);
    }
    sA[(dh*2+0)*256+jf]=p0;
    sA[(dh*2+1)*256+jf]=p1;
  }
  __syncthreads();
  float2 sinv;    // 1/wsum for q0,q1
  float2 effm2;
  {
    float dist[2][4];
    float2 mn2={FINF,FINF};
    if(tid<256){
      const float4 y2v=((const float4*)k2a)[jf];
      #pragma unroll
      for(int q=0;q<2;q++){
        const float x2=q2a[i0+q], B=1.f-x2;
        const float4 da=sA[q*256+jf], db=sA[(2+q)*256+jf];
        #pragma unroll
        for(int c=0;c<4;c++){
          const float y2=C4(y2v,c);
          const float dot=C4(da,c)+C4(db,c);
          const float A=1.f-2.f*dot+y2;
          const float den=fmaxf(1.f-2.f*dot+x2*y2,1e-15f);
          const float num2=fmaxf(A*A*x2 + B*B*y2 - 2.f*A*B*dot, 0.f);
          const float nn=sqrtf(num2/(den*den)+1e-15f);
          dist[q][c]=2.f*atanhf(fminf(nn,BND));
          C4(mn2,q)=fminf(C4(mn2,q),dist[q][c]);
        }
      }
    }
    mn2=blockMin512_v2(mn2,red);
    float w[2][4];
    float2 s2={0.f,0.f};
    if(tid<256){
      #pragma unroll
      for(int q=0;q<2;q++){
        #pragma unroll
        for(int c=0;c<4;c++){ w[q][c]=expf(C4(mn2,q)-dist[q][c]); C4(s2,q)+=w[q][c]; }
        ((float4*)&wl[q][0])[jf]=mk4(w[q]);
      }
    }
    s2=blockSum512_v2(s2,red);
    sinv.x=1.f/(s2.x+1e-8f); sinv.y=1.f/(s2.y+1e-8f);
    float2 e2={0.f,0.f};
    if(tid<256){
      #pragma unroll
      for(int q=0;q<2;q++){
        #pragma unroll
        for(int c=0;c<4;c++){
          const float p=w[q][c]*C4(sinv,q);
          C4(e2,q) -= p*logf(p+1e-8f);
        }
      }
    }
    e2=blockSum512_v2(e2,red);
    effm2.x=expf(e2.x); effm2.y=expf(e2.y);
  }

  // ================= P2: h + centroid in ONE vk sweep =================
  {
    // thread (dq5 in [0,32), g16 in [0,16)): 64 j's, row=128 floats
    float4 a0={0,0,0,0}, a1={0,0,0,0};
    #pragma unroll 4
    for(int jj=0;jj<64;jj++){
      const int j=jj*16+g16;
      const float4 y=((const float4*)(vk + (size_t)j*128))[dq5];
      const float u0=wl[0][j], u1=wl[1][j];
      FMA4(a0,u0,y); FMA4(a1,u1,y);
    }
    *(float4*)&pA[(g16*2+0)*128 + dq5*4]=a0;
    *(float4*)&pA[(g16*2+1)*128 + dq5*4]=a1;
  }
  __syncthreads();
  if(tid<256){
    const int q=tid>>7, dd=tid&127;   // dd<64: h-part (wave-aligned), dd>=64: centroid
    float s=0.f;
    #pragma unroll 8
    for(int gg=0;gg<16;gg++) s+=pA[(gg*2+q)*128+dd];
    s *= C4(sinv,q);
    if(dd<64){
      hl[q][dd]=s;
    }else{
      const int d=dd-64;
      const float n=sqrtf(waveSum(s*s)+1e-15f);
      const float ch=tanhf(n)*s/n;
      cv[q][d]=ch;
      const float c2v=waveSum(ch*ch);
      const float cd=waveSum(ch*vv[q][d]);
      if(d==0){ scal[q][0]=c2v; scal[q][2]=cd; }
    }
  }
  __syncthreads();

  // ================= PA: coefficients =================
  {
    float4 p0={0,0,0,0}, p1={0,0,0,0};
    #pragma unroll 8
    for(int dd=0; dd<32; ++dd){
      const int d=(dh<<5)+dd;
      const float4 y=kT4[d*256+jf];
      const float c0=cv[0][d], c1=cv[1][d];
      FMA4(p0,c0,y); FMA4(p1,c1,y);
    }
    sA[(dh*2+0)*256+jf]=p0;
    sA[(dh*2+1)*256+jf]=p1;
  }
  __syncthreads();
  {
    float var[2]={0.f,0.f};
    if(tid<256){
      const float4 y2v=((const float4*)k2a)[jf];
      #pragma unroll
      for(int q=0;q<2;q++){
        const float x2=scal[q][0];
        const float Bc=1.f-x2, mB=fmaxf(Bc,1e-15f), inv=C4(sinv,q);
        const float4 da=sA[q*256+jf], db=sA[(2+q)*256+jf];
        const float4 wv=((float4*)&wl[q][0])[jf];
        float ac[4], bc[4];
        #pragma unroll
        for(int c=0;c<4;c++){
          const float y2=C4(y2v,c);
          const float dot=C4(da,c)+C4(db,c);
          const float A=1.f-2.f*dot+y2;
          const float den=fmaxf(1.f-2.f*dot+x2*y2,1e-15f);
          const float num2=fmaxf(A*A*x2+Bc*Bc*y2-2.f*A*Bc*dot,0.f);
          const float nn=sqrtf(num2/(den*den)+1e-15f);
          const float art=atanhf(fminf(nn,BND));
          const float w=C4(wv,c);
          var[q] += w*inv*4.f*art*art;
          const float coef=sqrtf(w+1e-8f)*mB*art/(nn*den);
          ac[c]=-coef*A; bc[c]=coef*Bc;
        }
        ((float4*)&aal[q][0])[jf]=mk4(ac);
        ((float4*)&bbl[q][0])[jf]=mk4(bc);
      }
    }
    const float v0=waveSum(var[0]), v1=waveSum(var[1]);
    if((tid&63)==0){ varred[(tid>>6)*2]=v0; varred[(tid>>6)*2+1]=v1; }
  }
  __syncthreads();   // publishes aal/bbl/varred; sA reads done
  float* const prow0=&wl[0][0];   // wl dead; alias as prow[2][S]

  // ================= PB: 3 power iterations =================
  for(int it3=0; it3<3; ++it3){
    // pass 1: transposed dots with vv
    {
      float4 p0={0,0,0,0}, p1={0,0,0,0};
      #pragma unroll 8
      for(int dd=0; dd<32; ++dd){
        const int d=(dh<<5)+dd;
        const float4 y=kT4[d*256+jf];
        const float c0=vv[0][d], c1=vv[1][d];
        FMA4(p0,c0,y); FMA4(p1,c1,y);
      }
      sA[(dh*2+0)*256+jf]=p0;
      sA[(dh*2+1)*256+jf]=p1;
    }
    __syncthreads();
    // combine-p: prow + deferred sal
    {
      float sal[2]={0.f,0.f};
      if(tid<256){
        const float cdq[2]={scal[0][2], scal[1][2]};
        #pragma unroll
        for(int q=0;q<2;q++){
          const float4 da=sA[q*256+jf], db=sA[(2+q)*256+jf];
          const float4 av=((float4*)&aal[q][0])[jf];
          const float4 bv=((float4*)&bbl[q][0])[jf];
          float pr[4];
          #pragma unroll
          for(int c=0;c<4;c++){
            const float t=C4(da,c)+C4(db,c);
            const float p=C4(av,c)*cdq[q] + C4(bv,c)*t;
            pr[c]=p*C4(bv,c);
            sal[q] += p*C4(av,c);
          }
          ((float4*)&prow0[q*S])[jf]=mk4(pr);
        }
      }
      const float s0=waveSum(sal[0]), s1=waveSum(sal[1]);
      if((tid&63)==0){ salred[(tid>>6)*2]=s0; salred[(tid>>6)*2+1]=s1; }
    }
    __syncthreads();
    // pass 2: coalesced k_hyp sweep
    {
      float4 a0={0,0,0,0}, a1={0,0,0,0};
      #pragma unroll 4
      for(int jj=0;jj<32;jj++){
        const int j=jj*32+g;
        const float4 y=((const float4*)(k_hyp + j*D))[dq];
        const float u0=prow0[0*S+j], u1=prow0[1*S+j];
        FMA4(a0,u0,y); FMA4(a1,u1,y);
      }
      *(float4*)&pA[(g*2+0)*64+dq*4]=a0;
      *(float4*)&pA[(g*2+1)*64+dq*4]=a1;
    }
    __syncthreads();
    // vv-combine + next cdot
    if(tid<128){
      const int q=tid>>6, d=tid&63;
      float salt=0.f;
      #pragma unroll
      for(int k=0;k<8;k++) salt+=salred[k*2+q];
      float od=salt*cv[q][d];
      #pragma unroll 8
      for(int gg=0;gg<32;gg++) od += pA[(gg*2+q)*64+d];
      const float nn=sqrtf(waveSum(od*od));
      const float vn=od/fmaxf(nn,1e-12f);
      vv[q][d]=vn;
      const float cd=waveSum(cv[q][d]*vn);
      if(d==0) scal[q][2]=cd;
    }
    __syncthreads();
  }

  // ================= PC: epilogue + out GEMV =================
  if(tid<128){
    const int q=tid>>6, d=tid&63;
    const int i=i0+q;
    float vart=0.f;
    #pragma unroll
    for(int k=0;k<8;k++) vart+=varred[k*2+q];
    const float tns=vart - tau*C4(effm2,q);
    const float x2q_c=scal[q][0];
    const float vd=vv[q][d];
    const float hd=hl[q][d];
    const float qd=qv[q][d];
    const float q2=q2a[i];
    const float wpg=vd/fmaxf(1.f-x2q_c,1e-15f);
    const float nq=sqrtf(q2+1e-15f);
    const float qt=atanhf(fminf(nq,BND))*qd/nq;
    const float ncn=sqrtf(x2q_c+1e-15f);
    const float ct=atanhf(fminf(ncn,BND))*cv[q][d]/ncn;
    const float df=qt-ct;
    const float nd=sqrtf(waveSum(df*df));
    const float fb=df/fmaxf(nd,1e-8f);
    const float wp=(vart>1e-5f)?wpg:fb;
    const float hn=sqrtf(waveSum(hd*hd)+1e-15f);
    const float hc=asinhf(hn)*hd/(hn+1e-8f);
    const float x=waveSum(hc*wp);
    const float hmag=sqrtf(waveSum(hc*hc)+1e-15f);
    const float amp=(tns>0.f)? hmag*tanhf(tns) : 0.f;
    const float u0=gu[i*2], u1=gu[i*2+1];
    const float eg=(u0>=u1)?1.f:-1.f;
    const float dc=tanhf(eg*amp - x);
    const float hp=hc+dc*wp;
    const float hpn=sqrtf(waveSum(hp*hp)+1e-15f)+1e-8f;
    const float hpb=hp*(tanhf(hpn*ts_p[0])/hpn);
    const float n2=sqrtf(waveSum(hpb*hpb)+1e-15f);
    const float hyp=tanhf(n2)*hpb/n2;
    const float n3=sqrtf(waveSum(hyp*hyp)+1e-15f);
    const float bif=atanhf(fminf(n3,BND))*hyp/n3;
    const float gate=1.f/(1.f+expf(-gamma_p[0]));
    fus[q][d]=(1.f-gate)*hd + gate*bif;
  }
  __syncthreads();
  if(tid<128){
    const int q=tid>>6, d=tid&63;
    float acc=bo[d];
    const float4* wo4=(const float4*)(Wo + d*D);
    #pragma unroll
    for(int e=0;e<16;e++){
      float4 wv=wo4[e];
      acc += fus[q][4*e]*wv.x + fus[q][4*e+1]*wv.y + fus[q][4*e+2]*wv.z + fus[q][4*e+3]*wv.w;
    }
    out[(i0+q)*D+d]=acc;
  }
}

extern "C" void kernel_launch(void* const* d_in, const int* in_sizes, int n_in,
                              void* d_out, int out_size, void* d_ws, size_t ws_size,
                              hipStream_t stream)
{
  const float* qin=(const float*)d_in[0];
  const float* kin=(const float*)d_in[1];
  const float* vin=(const float*)d_in[2];
  const float* Wq=(const float*)d_in[3];
  const float* bq=(const float*)d_in[4];
  const float* Wk=(const float*)d_in[5];
  const float* bk=(const float*)d_in[6];
  const float* Wv=(const float*)d_in[7];
  const float* bv=(const float*)d_in[8];
  const float* Wo=(const float*)d_in[9];
  const float* bo=(const float*)d_in[10];
  const float* tau=(const float*)d_in[11];
  const float* gamma=(const float*)d_in[12];
  const float* tscale=(const float*)d_in[13];
  const float* gu=(const float*)d_in[14];
  const float* vrand=(const float*)d_in[15];
  float* out=(float*)d_out;

  float* p=(float*)d_ws;
  float* q_hyp=p; p+=S*D;
  float* k_hyp=p; p+=S*D;
  float* kT=p;    p+=S*D;
  float* vk=p;    p+=(size_t)S*128;
  float* v_r=p;   p+=S*D;
  float* q2=p;   p+=S;
  float* k2=p;   p+=S;

  k_proj<<<S/4,256,0,stream>>>(qin,kin,vin,Wq,bq,Wk,bk,Wv,bv,vrand,
                               q_hyp,k_hyp,kT,vk,q2,k2,v_r);
  k_main<<<S/2,512,0,stream>>>(q_hyp,k_hyp,kT,q2,k2,vk,v_r,
                               tau,gu,gamma,tscale,Wo,bo,out);
}

// Round 10
// 82.546 us; speedup vs baseline: 1.1529x; 1.1529x over previous
//
#include <hip/hip_runtime.h>
#include <hip/hip_fp16.h>
#include <math.h>

#define S 1024
#define D 64
#define BND 0.99999994f
#define FINF 3.4e38f
#define FMA4(acc,s,v) { (acc).x+=(s)*(v).x; (acc).y+=(s)*(v).y; (acc).z+=(s)*(v).z; (acc).w+=(s)*(v).w; }

__device__ __forceinline__ float waveSum(float v){
  #pragma unroll
  for(int o=32;o>0;o>>=1) v += __shfl_xor(v,o,64);
  return v;
}
// 512-thread packed 2-value reductions (one barrier pair each).
__device__ __forceinline__ float2 blockSum512_v2(float2 v, float* red){
  #pragma unroll
  for(int o=32;o>0;o>>=1){ v.x+=__shfl_xor(v.x,o,64); v.y+=__shfl_xor(v.y,o,64); }
  const int wid=threadIdx.x>>6;
  __syncthreads();
  if((threadIdx.x&63)==0){ red[wid*2]=v.x; red[wid*2+1]=v.y; }
  __syncthreads();
  float2 s={0.f,0.f};
  #pragma unroll
  for(int k=0;k<8;k++){ s.x+=red[k*2]; s.y+=red[k*2+1]; }
  return s;
}
__device__ __forceinline__ float2 blockMin512_v2(float2 v, float* red){
  #pragma unroll
  for(int o=32;o>0;o>>=1){ v.x=fminf(v.x,__shfl_xor(v.x,o,64)); v.y=fminf(v.y,__shfl_xor(v.y,o,64)); }
  const int wid=threadIdx.x>>6;
  __syncthreads();
  if((threadIdx.x&63)==0){ red[wid*2]=v.x; red[wid*2+1]=v.y; }
  __syncthreads();
  float2 s={red[0],red[1]};
  #pragma unroll
  for(int k=1;k<8;k++){ s.x=fminf(s.x,red[k*2]); s.y=fminf(s.y,red[k*2+1]); }
  return s;
}
// geodesic distance from (dot, |y|^2, |x|^2, 1-|x|^2)
__device__ __forceinline__ float distF(float dot, float y2, float x2, float B){
  const float A=1.f-2.f*dot+y2;
  const float den=fmaxf(1.f-2.f*dot+x2*y2,1e-15f);
  const float num2=fmaxf(A*A*x2 + B*B*y2 - 2.f*A*B*dot, 0.f);
  const float nn=sqrtf(num2/(den*den)+1e-15f);
  return 2.f*atanhf(fminf(nn,BND));
}

// K1: projections, expmap0(q/k), norms, v_r init, kT (fp32 transpose), kTp (fp16 d-pair transpose)
__global__ __launch_bounds__(64) void k_proj(
  const float* __restrict__ qin, const float* __restrict__ kin, const float* __restrict__ vin,
  const float* __restrict__ Wq, const float* __restrict__ bq,
  const float* __restrict__ Wk, const float* __restrict__ bk,
  const float* __restrict__ Wv, const float* __restrict__ bv,
  const float* __restrict__ vrand,
  float* __restrict__ q_hyp, float* __restrict__ k_hyp, float* __restrict__ kT,
  __half* __restrict__ kTp,
  float* __restrict__ vproj, float* __restrict__ kproj,
  float* __restrict__ q2, float* __restrict__ k2, float* __restrict__ v_r)
{
  const int i = blockIdx.x, d = threadIdx.x;
  __shared__ __align__(16) float lq[D], lk[D], lv[D];
  __shared__ __align__(16) float skh[D];
  lq[d]=qin[i*D+d]; lk[d]=kin[i*D+d]; lv[d]=vin[i*D+d];
  __syncthreads();
  float aq=bq[d], ak=bk[d], av=bv[d];
  const float4* wq4=(const float4*)(Wq + d*D);
  const float4* wk4=(const float4*)(Wk + d*D);
  const float4* wv4=(const float4*)(Wv + d*D);
  #pragma unroll
  for(int e=0;e<16;e++){
    float4 a=wq4[e], b=wk4[e], c=wv4[e];
    aq += lq[4*e]*a.x + lq[4*e+1]*a.y + lq[4*e+2]*a.z + lq[4*e+3]*a.w;
    ak += lk[4*e]*b.x + lk[4*e+1]*b.y + lk[4*e+2]*b.z + lk[4*e+3]*b.w;
    av += lv[4*e]*c.x + lv[4*e+1]*c.y + lv[4*e+2]*c.z + lv[4*e+3]*c.w;
  }
  float nq = sqrtf(waveSum(aq*aq)+1e-15f);
  float qh = tanhf(nq)*aq/nq;
  q_hyp[i*D+d]=qh;
  float q2v = waveSum(qh*qh);
  if(d==0) q2[i]=q2v;
  float nk = sqrtf(waveSum(ak*ak)+1e-15f);
  float kh = tanhf(nk)*ak/nk;
  k_hyp[i*D+d]=kh;
  kT[(size_t)d*S + i]=kh;
  skh[d]=kh;
  float k2v = waveSum(kh*kh);
  if(d==0) k2[i]=k2v;
  vproj[i*D+d]=av;
  kproj[i*D+d]=ak;
  float vr = vrand[i*D+d];
  float nn = sqrtf(waveSum(vr*vr));
  v_r[i*D+d] = vr/fmaxf(nn,1e-12f);
  __syncthreads();
  if(d<32){
    __half2 hp=__floats2half2_rn(skh[2*d], skh[2*d+1]);
    ((__half2*)kTp)[(size_t)d*S + i]=hp;   // [dp][j] half2 = (y[j][2dp], y[j][2dp+1])
  }
}

// K2 (weights+hcent): QB=2, 512 threads, grid 512.
//  P1: full-dot-per-thread (thread owns j=2t,2t+1): dist->min->w->wsum->entropy
//  P2: h & centroid (coalesced float4 sweep) + expmap0(centroid)
__global__ __launch_bounds__(512,4) void k_wc(
  const float* __restrict__ q_hyp, const float* __restrict__ kT,
  const float* __restrict__ q2a, const float* __restrict__ k2a,
  const float* __restrict__ vproj, const float* __restrict__ kproj,
  float* __restrict__ wbuf, float* __restrict__ wsum, float* __restrict__ effm,
  float* __restrict__ h, float* __restrict__ c_hyp, float* __restrict__ c2)
{
  const int i0=blockIdx.x*2, tid=threadIdx.x;
  __shared__ __align__(16) float qv[2][D];
  __shared__ __align__(16) float wl[2][S];
  __shared__ __align__(16) float4 sA[1024];   // h partials
  __shared__ __align__(16) float4 sB[1024];   // c partials
  __shared__ float red[16];
  if(tid<128) qv[tid>>6][tid&63]=q_hyp[i0*D+tid];
  __syncthreads();
  const float x20=q2a[i0], x21=q2a[i0+1];
  const float B0=1.f-x20, B1=1.f-x21;
  const int j0=2*tid;
  // ---- P1: full dots ----
  float t00=0.f,t01=0.f,t10=0.f,t11=0.f;   // t[j][q]
  #pragma unroll 8
  for(int d=0;d<64;++d){
    const float2 y=*(const float2*)(kT + (size_t)d*S + j0);
    const float c0=qv[0][d], c1=qv[1][d];
    t00+=y.x*c0; t01+=y.x*c1; t10+=y.y*c0; t11+=y.y*c1;
  }
  const float2 y2p=*(const float2*)(k2a + j0);
  const float ds00=distF(t00,y2p.x,x20,B0);
  const float ds10=distF(t10,y2p.y,x20,B0);
  const float ds01=distF(t01,y2p.x,x21,B1);
  const float ds11=distF(t11,y2p.y,x21,B1);
  float2 mn2={fminf(ds00,ds10), fminf(ds01,ds11)};
  mn2=blockMin512_v2(mn2,red);
  const float w00=expf(mn2.x-ds00), w10=expf(mn2.x-ds10);
  const float w01=expf(mn2.y-ds01), w11=expf(mn2.y-ds11);
  { float2 a={w00,w10}; *(float2*)&wl[0][j0]=a; *(float2*)(wbuf+(size_t)i0*S+j0)=a; }
  { float2 a={w01,w11}; *(float2*)&wl[1][j0]=a; *(float2*)(wbuf+(size_t)(i0+1)*S+j0)=a; }
  float2 s2={w00+w10, w01+w11};
  s2=blockSum512_v2(s2,red);           // also publishes wl
  const float s0=s2.x+1e-8f, s1=s2.y+1e-8f;
  if(tid==0){ wsum[i0]=s0; wsum[i0+1]=s1; }
  const float inv0=1.f/s0, inv1=1.f/s1;
  float2 e2={0.f,0.f};
  { const float p0=w00*inv0, p1=w10*inv0; e2.x -= p0*logf(p0+1e-8f)+p1*logf(p1+1e-8f); }
  { const float p0=w01*inv1, p1=w11*inv1; e2.y -= p0*logf(p0+1e-8f)+p1*logf(p1+1e-8f); }
  e2=blockSum512_v2(e2,red);
  if(tid==0){ effm[i0]=expf(e2.x); effm[i0+1]=expf(e2.y); }
  // ---- P2: h + centroid ----
  const int dq=tid&15, g=tid>>4;
  float* const pA=(float*)sA;
  float* const pB=(float*)sB;
  {
    float4 ah0={0,0,0,0}, ah1={0,0,0,0}, ac0={0,0,0,0}, ac1={0,0,0,0};
    #pragma unroll 4
    for(int jj=0;jj<32;jj++){
      const int j=jj*32+g;
      const float4 yv=((const float4*)(vproj + j*D))[dq];
      const float4 yk=((const float4*)(kproj + j*D))[dq];
      const float u0=wl[0][j], u1=wl[1][j];
      FMA4(ah0,u0,yv); FMA4(ah1,u1,yv);
      FMA4(ac0,u0,yk); FMA4(ac1,u1,yk);
    }
    *(float4*)&pA[(g*2+0)*64+dq*4]=ah0;
    *(float4*)&pA[(g*2+1)*64+dq*4]=ah1;
    *(float4*)&pB[(g*2+0)*64+dq*4]=ac0;
    *(float4*)&pB[(g*2+1)*64+dq*4]=ac1;
  }
  __syncthreads();
  if(tid<128){
    const int q=tid>>6, d=tid&63;
    float hs=0.f, cs=0.f;
    #pragma unroll 8
    for(int gg=0;gg<32;gg++){ hs+=pA[(gg*2+q)*64+d]; cs+=pB[(gg*2+q)*64+d]; }
    const float invq = q ? inv1 : inv0;
    h[(i0+q)*D+d]=hs*invq;
    const float ca=cs*invq;
    const float n=sqrtf(waveSum(ca*ca)+1e-15f);
    const float ch=tanhf(n)*ca/n;
    c_hyp[(i0+q)*D+d]=ch;
    const float c2v=waveSum(ch*ch);
    if(d==0) c2[i0+q]=c2v;
  }
}

// K3 (ab+power+final): QB=2, 512 threads, grid 512.
//  PA: full-dot coefs (fp32 kT), var; PB: 3 iters (pass1 = fp16 full-dot, pass2 = float4 k_hyp);
//  PC: bifurcation epilogue + out GEMV
__global__ __launch_bounds__(512,4) void k_pmega(
  const float* __restrict__ c_hyp, const float* __restrict__ k_hyp,
  const float* __restrict__ kT, const __half* __restrict__ kTp,
  const float* __restrict__ c2a, const float* __restrict__ k2a,
  const float* __restrict__ wbuf, const float* __restrict__ wsum,
  const float* __restrict__ effm, const float* __restrict__ tau_p,
  const float* __restrict__ h, const float* __restrict__ q_hyp,
  const float* __restrict__ q2a, const float* __restrict__ v_r,
  const float* __restrict__ gu, const float* __restrict__ gamma_p,
  const float* __restrict__ ts_p, const float* __restrict__ Wo,
  const float* __restrict__ bo, float* __restrict__ out)
{
  const int i0=blockIdx.x*2, tid=threadIdx.x;
  __shared__ __align__(16) float cv[2][D];
  __shared__ __align__(16) float vv[2][D];
  __shared__ __align__(16) float aal[2][S];
  __shared__ __align__(16) float bbl[2][S];
  __shared__ __align__(16) float prow[2][S];
  __shared__ __align__(16) float4 sA[1024];   // pass2 partials (16KB)
  __shared__ __align__(16) float fus[2][D];
  __shared__ float red[16];
  __shared__ float scd[2];                    // cdot per query
  float* const pA=(float*)sA;

  if(tid<128){
    const int q=tid>>6, d=tid&63;
    const float ch=c_hyp[i0*D+tid];
    const float vr=v_r[i0*D+tid];
    cv[q][d]=ch; vv[q][d]=vr;
    const float cd=waveSum(ch*vr);
    if(d==0) scd[q]=cd;
  }
  __syncthreads();
  const float x20=c2a[i0], x21=c2a[i0+1];
  const float Bc0=1.f-x20, Bc1=1.f-x21;
  const float mB0=fmaxf(Bc0,1e-15f), mB1=fmaxf(Bc1,1e-15f);
  const float inv0=1.f/wsum[i0], inv1=1.f/wsum[i0+1];
  const int j0=2*tid;
  const int dq=tid&15, g=tid>>4;
  const float tau=tau_p[0];

  // ---- PA: full-dot coefficients ----
  float2 var2;
  {
    float u00=0.f,u01=0.f,u10=0.f,u11=0.f;   // [j][q]
    #pragma unroll 8
    for(int d=0;d<64;++d){
      const float2 y=*(const float2*)(kT + (size_t)d*S + j0);
      const float c0=cv[0][d], c1=cv[1][d];
      u00+=y.x*c0; u01+=y.x*c1; u10+=y.y*c0; u11+=y.y*c1;
    }
    const float2 y2p=*(const float2*)(k2a + j0);
    const float2 w0=*(const float2*)(wbuf+(size_t)i0*S+j0);
    const float2 w1=*(const float2*)(wbuf+(size_t)(i0+1)*S+j0);
    float var0=0.f, var1=0.f;
    float a00,a10,a01,a11,b00,b10,b01,b11;
    {
      const float A=1.f-2.f*u00+y2p.x;
      const float den=fmaxf(1.f-2.f*u00+x20*y2p.x,1e-15f);
      const float num2=fmaxf(A*A*x20+Bc0*Bc0*y2p.x-2.f*A*Bc0*u00,0.f);
      const float nn=sqrtf(num2/(den*den)+1e-15f);
      const float art=atanhf(fminf(nn,BND));
      var0 += w0.x*inv0*4.f*art*art;
      const float coef=sqrtf(w0.x+1e-8f)*mB0*art/(nn*den);
      a00=-coef*A; b00=coef*Bc0;
    }
    {
      const float A=1.f-2.f*u10+y2p.y;
      const float den=fmaxf(1.f-2.f*u10+x20*y2p.y,1e-15f);
      const float num2=fmaxf(A*A*x20+Bc0*Bc0*y2p.y-2.f*A*Bc0*u10,0.f);
      const float nn=sqrtf(num2/(den*den)+1e-15f);
      const float art=atanhf(fminf(nn,BND));
      var0 += w0.y*inv0*4.f*art*art;
      const float coef=sqrtf(w0.y+1e-8f)*mB0*art/(nn*den);
      a10=-coef*A; b10=coef*Bc0;
    }
    {
      const float A=1.f-2.f*u01+y2p.x;
      const float den=fmaxf(1.f-2.f*u01+x21*y2p.x,1e-15f);
      const float num2=fmaxf(A*A*x21+Bc1*Bc1*y2p.x-2.f*A*Bc1*u01,0.f);
      const float nn=sqrtf(num2/(den*den)+1e-15f);
      const float art=atanhf(fminf(nn,BND));
      var1 += w1.x*inv1*4.f*art*art;
      const float coef=sqrtf(w1.x+1e-8f)*mB1*art/(nn*den);
      a01=-coef*A; b01=coef*Bc1;
    }
    {
      const float A=1.f-2.f*u11+y2p.y;
      const float den=fmaxf(1.f-2.f*u11+x21*y2p.y,1e-15f);
      const float num2=fmaxf(A*A*x21+Bc1*Bc1*y2p.y-2.f*A*Bc1*u11,0.f);
      const float nn=sqrtf(num2/(den*den)+1e-15f);
      const float art=atanhf(fminf(nn,BND));
      var1 += w1.y*inv1*4.f*art*art;
      const float coef=sqrtf(w1.y+1e-8f)*mB1*art/(nn*den);
      a11=-coef*A; b11=coef*Bc1;
    }
    { float2 t={a00,a10}; *(float2*)&aal[0][j0]=t; }
    { float2 t={a01,a11}; *(float2*)&aal[1][j0]=t; }
    { float2 t={b00,b10}; *(float2*)&bbl[0][j0]=t; }
    { float2 t={b01,b11}; *(float2*)&bbl[1][j0]=t; }
    float2 v2={var0,var1};
    var2=blockSum512_v2(v2,red);   // also publishes aal/bbl
  }

  // ---- PB: 3 power iterations ----
  float2 sal2;
  for(int it3=0; it3<3; ++it3){
    // pass 1: fp16 full dots (thread owns j0,j0+1)
    float t00=0.f,t01=0.f,t10=0.f,t11=0.f;
    #pragma unroll 8
    for(int dp=0;dp<32;++dp){
      const __half2 h0=((const __half2*)kTp)[(size_t)dp*S + j0];
      const __half2 h1=((const __half2*)kTp)[(size_t)dp*S + j0+1];
      const float2 f0=__half22float2(h0);
      const float2 f1=__half22float2(h1);
      const float2 v0=*(const float2*)&vv[0][2*dp];
      const float2 v1=*(const float2*)&vv[1][2*dp];
      t00 += f0.x*v0.x + f0.y*v0.y;
      t01 += f0.x*v1.x + f0.y*v1.y;
      t10 += f1.x*v0.x + f1.y*v0.y;
      t11 += f1.x*v1.x + f1.y*v1.y;
    }
    {
      const float cd0=scd[0], cd1=scd[1];
      const float2 a0=*(const float2*)&aal[0][j0], b0=*(const float2*)&bbl[0][j0];
      const float2 a1=*(const float2*)&aal[1][j0], b1=*(const float2*)&bbl[1][j0];
      const float p00=a0.x*cd0+b0.x*t00, p10=a0.y*cd0+b0.y*t10;
      const float p01=a1.x*cd1+b1.x*t01, p11=a1.y*cd1+b1.y*t11;
      { float2 t={p00*b0.x, p10*b0.y}; *(float2*)&prow[0][j0]=t; }
      { float2 t={p01*b1.x, p11*b1.y}; *(float2*)&prow[1][j0]=t; }
      float2 s={p00*a0.x+p10*a0.y, p01*a1.x+p11*a1.y};
      sal2=blockSum512_v2(s,red);   // also publishes prow
    }
    // pass 2: coalesced k_hyp sweep
    {
      float4 a0={0,0,0,0}, a1={0,0,0,0};
      #pragma unroll 4
      for(int jj=0;jj<32;jj++){
        const int j=jj*32+g;
        const float4 y=((const float4*)(k_hyp + j*D))[dq];
        const float u0=prow[0][j], u1=prow[1][j];
        FMA4(a0,u0,y); FMA4(a1,u1,y);
      }
      *(float4*)&pA[(g*2+0)*64+dq*4]=a0;
      *(float4*)&pA[(g*2+1)*64+dq*4]=a1;
    }
    __syncthreads();
    // vv-combine + next cdot
    if(tid<128){
      const int q=tid>>6, d=tid&63;
      float od=(q?sal2.y:sal2.x)*cv[q][d];
      #pragma unroll 8
      for(int gg=0;gg<32;gg++) od += pA[(gg*2+q)*64+d];
      const float nn=sqrtf(waveSum(od*od));
      const float vn=od/fmaxf(nn,1e-12f);
      vv[q][d]=vn;
      const float cd=waveSum(cv[q][d]*vn);
      if(d==0) scd[q]=cd;
    }
    __syncthreads();
  }

  // ---- PC: epilogue + out GEMV ----
  if(tid<128){
    const int q=tid>>6, d=tid&63;
    const int i=i0+q;
    const float vart = q ? var2.y : var2.x;
    const float tns = vart - tau*effm[i];
    const float x2q_c = q ? x21 : x20;
    const float vd=vv[q][d];
    const float hd=h[i*D+d];
    const float qd=q_hyp[i*D+d];
    const float q2=q2a[i];
    const float wpg=vd/fmaxf(1.f-x2q_c,1e-15f);
    const float nq=sqrtf(q2+1e-15f);
    const float qt=atanhf(fminf(nq,BND))*qd/nq;
    const float ncn=sqrtf(x2q_c+1e-15f);
    const float ct=atanhf(fminf(ncn,BND))*cv[q][d]/ncn;
    const float df=qt-ct;
    const float nd=sqrtf(waveSum(df*df));
    const float fb=df/fmaxf(nd,1e-8f);
    const float wp=(vart>1e-5f)?wpg:fb;
    const float hn=sqrtf(waveSum(hd*hd)+1e-15f);
    const float hc=asinhf(hn)*hd/(hn+1e-8f);
    const float x=waveSum(hc*wp);
    const float hmag=sqrtf(waveSum(hc*hc)+1e-15f);
    const float amp=(tns>0.f)? hmag*tanhf(tns) : 0.f;
    const float u0=gu[i*2], u1=gu[i*2+1];
    const float eg=(u0>=u1)?1.f:-1.f;
    const float dc=tanhf(eg*amp - x);
    const float hp=hc+dc*wp;
    const float hpn=sqrtf(waveSum(hp*hp)+1e-15f)+1e-8f;
    const float hpb=hp*(tanhf(hpn*ts_p[0])/hpn);
    const float n2=sqrtf(waveSum(hpb*hpb)+1e-15f);
    const float hyp=tanhf(n2)*hpb/n2;
    const float n3=sqrtf(waveSum(hyp*hyp)+1e-15f);
    const float bif=atanhf(fminf(n3,BND))*hyp/n3;
    const float gate=1.f/(1.f+expf(-gamma_p[0]));
    fus[q][d]=(1.f-gate)*hd + gate*bif;
  }
  __syncthreads();
  if(tid<128){
    const int q=tid>>6, d=tid&63;
    float acc=bo[d];
    const float4* wo4=(const float4*)(Wo + d*D);
    #pragma unroll
    for(int e=0;e<16;e++){
      float4 wv=wo4[e];
      acc += fus[q][4*e]*wv.x + fus[q][4*e+1]*wv.y + fus[q][4*e+2]*wv.z + fus[q][4*e+3]*wv.w;
    }
    out[(i0+q)*D+d]=acc;
  }
}

extern "C" void kernel_launch(void* const* d_in, const int* in_sizes, int n_in,
                              void* d_out, int out_size, void* d_ws, size_t ws_size,
                              hipStream_t stream)
{
  const float* qin=(const float*)d_in[0];
  const float* kin=(const float*)d_in[1];
  const float* vin=(const float*)d_in[2];
  const float* Wq=(const float*)d_in[3];
  const float* bq=(const float*)d_in[4];
  const float* Wk=(const float*)d_in[5];
  const float* bk=(const float*)d_in[6];
  const float* Wv=(const float*)d_in[7];
  const float* bv=(const float*)d_in[8];
  const float* Wo=(const float*)d_in[9];
  const float* bo=(const float*)d_in[10];
  const float* tau=(const float*)d_in[11];
  const float* gamma=(const float*)d_in[12];
  const float* tscale=(const float*)d_in[13];
  const float* gu=(const float*)d_in[14];
  const float* vrand=(const float*)d_in[15];
  float* out=(float*)d_out;

  float* p=(float*)d_ws;
  float* q_hyp=p; p+=S*D;
  float* k_hyp=p; p+=S*D;
  float* kT=p;    p+=S*D;
  float* vproj=p; p+=S*D;
  float* kproj=p; p+=S*D;
  float* v_r=p;   p+=S*D;
  float* h=p;     p+=S*D;
  float* c_hyp=p; p+=S*D;
  float* q2=p;   p+=S;
  float* k2=p;   p+=S;
  float* c2=p;   p+=S;
  float* wsum=p; p+=S;
  float* effm=p; p+=S;
  __half* kTp=(__half*)p; p+=(S*D)/2;
  float* wbuf=p; p+=(size_t)S*S;

  k_proj<<<S,64,0,stream>>>(qin,kin,vin,Wq,bq,Wk,bk,Wv,bv,vrand,
                            q_hyp,k_hyp,kT,kTp,vproj,kproj,q2,k2,v_r);
  k_wc<<<S/2,512,0,stream>>>(q_hyp,kT,q2,k2,vproj,kproj,
                             wbuf,wsum,effm,h,c_hyp,c2);
  k_pmega<<<S/2,512,0,stream>>>(c_hyp,k_hyp,kT,kTp,c2,k2,wbuf,wsum,effm,tau,
                                h,q_hyp,q2,v_r,gu,gamma,tscale,Wo,bo,out);
}